// Round 10
// baseline (121.032 us; speedup 1.0000x reference)
//
#include <hip/hip_runtime.h>
#include <stdint.h>

#define N_NODES 8192
#define N_EDGES 262144
#define IN_C    512
#define OUT_C   512
#define MAX_DEG 128   // raw degree Poisson(~32); max over 8192 rows ~65 (R0/R6 128-cap passed)
#define W_ELEMS (OUT_C * IN_C)                   // 262144
#define BM_WORDS (N_NODES * (N_NODES / 32))      // 2097152 u32 = 8 MB adjacency bitmap

typedef __attribute__((ext_vector_type(8))) short short8;   // 8 bf16 in 4 VGPRs
typedef __attribute__((ext_vector_type(4))) float f32x4;

// ---- fp32 -> bf16 (RNE) ----
__device__ inline uint16_t f2bf(float f) {
    uint32_t u = __float_as_uint(f);
    uint32_t r = (u + 0x7FFFu + ((u >> 16) & 1u)) >> 16;
    return (uint16_t)r;
}

#define GLOAD_LDS16(g, l)                                                        \
    __builtin_amdgcn_global_load_lds(                                            \
        (const __attribute__((address_space(1))) uint32_t*)(g),                  \
        (__attribute__((address_space(3))) uint32_t*)(l), 16, 0, 0)

// W -> bf16; zero degree counters and the adjacency bitmap.
__global__ __launch_bounds__(256) void convert_k(const float* __restrict__ W,
                                                 uint16_t* __restrict__ wb,
                                                 int* __restrict__ cnt,
                                                 uint4* __restrict__ bm) {
    int tid = blockIdx.x * 256 + threadIdx.x;            // 2048 blocks * 256 = 524288
    if (tid < N_NODES) cnt[tid] = 0;
    bm[tid] = make_uint4(0u, 0u, 0u, 0u);                // 524288 * 16B = 8 MB
    if (tid < W_ELEMS / 8) {
        int i = tid * 8;
        float4 v0 = *(const float4*)(W + i);
        float4 v1 = *(const float4*)(W + i + 4);
        ushort4 o0, o1;
        o0.x = f2bf(v0.x); o0.y = f2bf(v0.y); o0.z = f2bf(v0.z); o0.w = f2bf(v0.w);
        o1.x = f2bf(v1.x); o1.y = f2bf(v1.y); o1.z = f2bf(v1.z); o1.w = f2bf(v1.w);
        *(ushort4*)(wb + i)     = o0;
        *(ushort4*)(wb + i + 4) = o1;
    }
}

// ---- fused: blocks [0,512) = GEMM tiles; blocks [512,1568) = bitmap-dedup edge scatter ----
// GEMM: h = x @ W^T + b (bf16 MFMA 16x16x32, fp32 accum, bf16 out)
//   64x128 tile, BK=64 -> 512 blocks = 2 blocks/CU (R9's 256-block grid left 1 block/CU:
//   zero cross-block overlap, every barrier exposed the staging drain; m114/m97 implicit
//   wave-level overlap needs >=2 blocks/CU). LDS 24 KB/block -> 2 co-resident easily.
//   B-slab: global_load_lds width=16 from wb. A-slab: reg-staged fp32 x + in-register f2bf.
//   Operand-SWAPPED mfma(Wfrag, xfrag): lane holds 4 consecutive out-channels -> 8-B C-stores
//   XCD swizzle: 4 ncol-blocks sharing an A-panel keep the same (bid&7) residue -> same XCD
// Scatter: atomicOr claims bit (r,c) in the 8 MB bitmap; first claimer appends c to nbr[r].
__global__ __launch_bounds__(256) void gemm_scatter_k(const float* __restrict__ x,
                                                      const uint16_t* __restrict__ wb,
                                                      const float* __restrict__ bias,
                                                      uint16_t* __restrict__ h,
                                                      const int* __restrict__ ei,
                                                      int* __restrict__ cnt,
                                                      uint16_t* __restrict__ nbr,
                                                      uint32_t* __restrict__ bm) {
    __shared__ uint16_t lA[64 * 64];    // 8 KB, linear [row][k]
    __shared__ uint16_t lB[128 * 64];   // 16 KB
    const int bid = blockIdx.x;
    if (bid < 512) {
        // ---------------- GEMM path ----------------
        const int tid  = threadIdx.x;
        const int wave = tid >> 6;
        const int lane = tid & 63;
        const int quad = lane >> 4;
        const int l16  = lane & 15;
        // bijective (bid) -> (mrow in [0,128), ncol in [0,4)); A-panel sharers on one XCD
        const int mrow = (bid & 7) * 16 + (bid >> 5);
        const int ncol = (bid >> 3) & 3;
        const int m0 = mrow * 64;             // block row base (64 rows)
        const int n0 = ncol * 128;            // block col (out-channel) base (128 cols)
        const int wn = wave;                  // wave n-slice: 32 cols each

        // B staging: each global_load_lds_dwordx4 = 64 lanes x 16 B = 1 KB = 8 rows
        const int srow = wave * 32 + (lane >> 3);       // staged row, +8 per it
        const int scol = (lane & 7) * 8;                // staged k-offset (elements)
        uint16_t* lBdst = &lB[wave * 32 * 64];          // wave-uniform LDS base

        // A staging: 4 rounds x 16 rows; thread covers (row = rnd*16 + tid>>4, 4 k-elems)
        const int arow = tid >> 4;                      // 0..15
        const int acol = (tid & 15) * 4;                // 0..60

        f32x4 acc[4][2];
        #pragma unroll
        for (int a = 0; a < 4; a++)
            #pragma unroll
            for (int s = 0; s < 2; s++) acc[a][s] = (f32x4){0.f, 0.f, 0.f, 0.f};

        for (int k0 = 0; k0 < IN_C; k0 += 64) {
            // ---- issue B-slab gload_lds (4 x 1 KB per wave) ----
            #pragma unroll
            for (int it = 0; it < 4; it++)
                GLOAD_LDS16(wb + (n0 + srow + it * 8) * IN_C + k0 + scol, lBdst + it * 8 * 64);
            // ---- A-slab: fp32 load -> bf16 cvt -> LDS (4 rounds x 16 rows) ----
            float4 av[4];
            #pragma unroll
            for (int rnd = 0; rnd < 4; rnd++)
                av[rnd] = *(const float4*)(x + (size_t)(m0 + rnd * 16 + arow) * IN_C + k0 + acol);
            #pragma unroll
            for (int rnd = 0; rnd < 4; rnd++) {
                ushort4 o;
                o.x = f2bf(av[rnd].x); o.y = f2bf(av[rnd].y);
                o.z = f2bf(av[rnd].z); o.w = f2bf(av[rnd].w);
                *(ushort4*)&lA[(rnd * 16 + arow) * 64 + acol] = o;
            }
            __syncthreads();   // drains vmcnt (B gloads) + lgkm (A ds_writes)
            // ---- compute: 2 k-halves x 8 MFMA ----
            #pragma unroll
            for (int kk = 0; kk < 2; kk++) {
                short8 af[4], bfr[2];
                #pragma unroll
                for (int a = 0; a < 4; a++)
                    af[a] = *(const short8*)&lA[(a * 16 + l16) * 64 + kk * 32 + quad * 8];
                #pragma unroll
                for (int s = 0; s < 2; s++)
                    bfr[s] = *(const short8*)&lB[(wn * 32 + s * 16 + l16) * 64 + kk * 32 + quad * 8];
                #pragma unroll
                for (int a = 0; a < 4; a++)
                    #pragma unroll
                    for (int s = 0; s < 2; s++)
                        acc[a][s] = __builtin_amdgcn_mfma_f32_16x16x32_bf16(bfr[s], af[a], acc[a][s], 0, 0, 0);
            }
            __syncthreads();
        }
        // D': col=l16 -> m (x-row), row=quad*4+r -> n (out channel). 4 consecutive n per lane.
        #pragma unroll
        for (int s = 0; s < 2; s++) {
            int col_n0 = n0 + wn * 32 + s * 16 + quad * 4;
            float4 bv = *(const float4*)(bias + col_n0);
            #pragma unroll
            for (int a = 0; a < 4; a++) {
                int row_m = m0 + a * 16 + l16;
                ushort4 o;
                o.x = f2bf(acc[a][s][0] + bv.x);
                o.y = f2bf(acc[a][s][1] + bv.y);
                o.z = f2bf(acc[a][s][2] + bv.z);
                o.w = f2bf(acc[a][s][3] + bv.w);
                *(ushort4*)(h + row_m * OUT_C + col_n0) = o;   // 8-B packed store
            }
        }
    } else {
        // ---------------- scatter path (bitmap dedup) ----------------
        int t = (bid - 512) * 256 + threadIdx.x;
        int r, c;
        if (t < N_EDGES) {
            r = ei[t];             // edge_index[0][t]
            c = ei[N_EDGES + t];   // edge_index[1][t]
        } else if (t < N_EDGES + N_NODES) {
            r = t - N_EDGES; c = r;   // self loop
        } else return;
        uint32_t w   = (uint32_t)r * (uint32_t)(N_NODES / 32) + ((uint32_t)c >> 5);
        uint32_t bit = 1u << (c & 31);
        uint32_t old = atomicOr(&bm[w], bit);
        if (!(old & bit)) {                       // first claimer of (r,c)
            int pos = atomicAdd(&cnt[r], 1);
            if (pos < MAX_DEG) nbr[r * MAX_DEG + pos] = (uint16_t)c;
        }
    }
}

// ---- out[i] = rsqrt(deg_i) * sum_j rsqrt(deg_j) * h[j]; bf16 h, channel-QUARTERED ----
// R5 structure (one 64-thread wave per (node, quarter) unit, 32768 blocks). q = bid & 3;
// under bid%8 -> XCD round-robin each XCD touches only its 2 MB h-quarter -> fits the
// private 4 MiB L2. Per-channel summation order identical.
__global__ __launch_bounds__(64) void aggregate_k(const int* __restrict__ cnt,
                                                  const uint16_t* __restrict__ nbr,
                                                  const uint32_t* __restrict__ h2,
                                                  float* __restrict__ out) {
    const int i    = blockIdx.x >> 2;
    const int q    = blockIdx.x & 3;
    const int lane = threadIdx.x;
    int m = cnt[i]; if (m > MAX_DEG) m = MAX_DEG;

    __shared__ uint16_t jl[MAX_DEG];
    __shared__ float    dl[MAX_DEG];
    for (int t = lane; t < m; t += 64) {
        uint16_t j = nbr[i * MAX_DEG + t];
        jl[t] = j;
        dl[t] = rsqrtf((float)cnt[j]);   // cnt is 32 KB -> L1/L2 resident
    }
    __syncthreads();

    const uint32_t* hp = h2 + q * 64 + lane;   // 256 uints per row; quarter = 64 uints
    float s0 = 0.f, s1 = 0.f;
    #pragma unroll 8
    for (int l = 0; l < m; l++) {
        uint32_t u = hp[(int)jl[l] * 256];                // 256 B coalesced gather, L2-local
        float dj = dl[l];
        s0 += dj * __uint_as_float(u << 16);              // even channel
        s1 += dj * __uint_as_float(u & 0xFFFF0000u);      // odd channel
    }
    float di = rsqrtf((float)m);
    int c = q * 128 + lane * 2;
    float2 o = {di * s0, di * s1};
    *(float2*)(out + i * OUT_C + c) = o;
}

extern "C" void kernel_launch(void* const* d_in, const int* in_sizes, int n_in,
                              void* d_out, int out_size, void* d_ws, size_t ws_size,
                              hipStream_t stream) {
    const float* x  = (const float*)d_in[0];
    const int*   ei = (const int*)  d_in[1];
    const float* W  = (const float*)d_in[2];
    const float* b  = (const float*)d_in[3];
    float* out = (float*)d_out;
    char* ws = (char*)d_ws;

    // ws layout (bytes)
    const size_t CNT_OFF = 0;                       // 32 KB
    const size_t BM_OFF  = 32768;                   // 8 MB bitmap
    const size_t NBR_OFF = BM_OFF + 8388608;        // 2 MB (u16 * 8192 * 128)
    const size_t WB_OFF  = NBR_OFF + 2097152;       // 512 KB
    const size_t H_OFF   = WB_OFF + 524288;         // 8 MB (bf16)
    int*      cnt = (int*)     (ws + CNT_OFF);
    uint32_t* bm  = (uint32_t*)(ws + BM_OFF);
    uint16_t* nbr = (uint16_t*)(ws + NBR_OFF);
    uint16_t* wb  = (uint16_t*)(ws + WB_OFF);
    uint16_t* h   = (uint16_t*)(ws + H_OFF);

    convert_k<<<BM_WORDS / 4 / 256, 256, 0, stream>>>(W, wb, cnt, (uint4*)bm);

    gemm_scatter_k<<<512 + (N_EDGES + N_NODES + 255) / 256, 256, 0, stream>>>(
        x, wb, b, h, ei, cnt, nbr, bm);

    aggregate_k<<<N_NODES * 4, 64, 0, stream>>>(cnt, nbr, (const uint32_t*)h, out);
}